// Round 1
// baseline (517.410 us; speedup 1.0000x reference)
//
#include <hip/hip_runtime.h>
#include <math.h>

// Problem constants (fixed by the reference):
#define GP 8
#define GB 256
#define GN 512
#define GK 64

// One block per (p, b). Phase 1: WRx[k] = WR[p,b,k,:]·v_tm1 (and Wx with v_t).
// Phase 2: WLWRx[n] = WL[p,b,n,:]·WRx (and v_next row with Wx when selected).
// All traffic: 128 KB WR + 128 KB WL per block, single pass -> memory-bound.
__global__ __launch_bounds__(256) void ghu_fused(
    const float* __restrict__ WL,
    const float* __restrict__ WR,
    const float* __restrict__ v_tm1,
    const float* __restrict__ v_t,
    const int*   __restrict__ ac_idx,
    const int*   __restrict__ pc_mask,
    float* __restrict__ out,       // [GB*GN v_next][GP*GB*GN dWL][GP*GB*GN dWR]
    float g, float inv_n)
{
    const int b    = blockIdx.x;
    const int p    = blockIdx.y;
    const int tid  = threadIdx.x;
    const int wave = tid >> 6;
    const int lane = tid & 63;

    __shared__ float s_vtm1[GN];
    __shared__ float s_vt[GN];
    __shared__ float s_WRx[GK];
    __shared__ float s_Wx[GK];
    __shared__ float s_dWL[GN];
    __shared__ float s_vnext[GN];

    // Stage v vectors (coalesced, L2-resident: only 1 MB total across grid)
    s_vtm1[tid]       = v_tm1[b * GN + tid];
    s_vtm1[tid + 256] = v_tm1[b * GN + tid + 256];
    s_vt[tid]         = v_t[b * GN + tid];
    s_vt[tid + 256]   = v_t[b * GN + tid + 256];
    __syncthreads();

    const bool  sel   = (ac_idx[b] == p);          // block-uniform
    const float maskv = (float)pc_mask[b * GP + p];

    // Hoisted per-lane v slices as float4 LDS reads (ds_read_b128, conflict-free)
    const float4 u0 = ((const float4*)s_vtm1)[lane];
    const float4 u1 = ((const float4*)s_vtm1)[lane + 64];
    const float4 t0 = ((const float4*)s_vt)[lane];
    const float4 t1 = ((const float4*)s_vt)[lane + 64];

    // ---- Phase 1: one wave per row k (N=512 = 64 lanes x 8 floats) ----
    const float* WRpb = WR + (size_t)(p * GB + b) * (GK * GN);
    for (int k = wave; k < GK; k += 4) {
        const float4* row = (const float4*)(WRpb + k * GN);
        const float4 a0 = row[lane];
        const float4 a1 = row[lane + 64];
        float acc  = a0.x*u0.x + a0.y*u0.y + a0.z*u0.z + a0.w*u0.w
                   + a1.x*u1.x + a1.y*u1.y + a1.z*u1.z + a1.w*u1.w;
        float acc2 = a0.x*t0.x + a0.y*t0.y + a0.z*t0.z + a0.w*t0.w
                   + a1.x*t1.x + a1.y*t1.y + a1.z*t1.z + a1.w*t1.w;
        #pragma unroll
        for (int off = 32; off > 0; off >>= 1) {
            acc  += __shfl_down(acc,  off);
            acc2 += __shfl_down(acc2, off);
        }
        if (lane == 0) {
            s_WRx[k] = acc;
            s_Wx[k]  = acc2;   // only consumed when sel, harmless otherwise
        }
    }
    __syncthreads();

    // ---- Phase 2: 16-lane group per row n (K=64 = 16 lanes x 4 floats) ----
    const int grp = lane >> 4;
    const int sub = lane & 15;
    const float4 wr4 = ((const float4*)s_WRx)[sub];
    const float4 wx4 = ((const float4*)s_Wx)[sub];

    const float* WLpb = WL + (size_t)(p * GB + b) * (GN * GK);
    for (int i = 0; i < GN / 16; ++i) {
        const int row = i * 16 + wave * 4 + grp;
        const float4 a = ((const float4*)(WLpb + row * GK))[sub];
        float acc  = a.x*wr4.x + a.y*wr4.y + a.z*wr4.z + a.w*wr4.w;
        float acc2 = a.x*wx4.x + a.y*wx4.y + a.z*wx4.z + a.w*wx4.w;
        #pragma unroll
        for (int off = 1; off < 16; off <<= 1) {
            acc  += __shfl_xor(acc,  off);
            acc2 += __shfl_xor(acc2, off);
        }
        if (sub == 0) {
            s_dWL[row]   = (g * s_vt[row] - acc) * maskv;
            s_vnext[row] = tanhf(acc2);
        }
    }
    __syncthreads();

    // ---- Epilogue: coalesced contiguous writes ----
    const size_t pbN = (size_t)(p * GB + b) * GN;
    float* dWL_out = out + (size_t)GB * GN + pbN;
    float* dWR_out = out + (size_t)GB * GN + (size_t)GP * GB * GN + pbN;

    dWL_out[tid]       = s_dWL[tid];
    dWL_out[tid + 256] = s_dWL[tid + 256];

    const float sc = maskv * inv_n;
    dWR_out[tid]       = s_vtm1[tid] * sc;
    dWR_out[tid + 256] = s_vtm1[tid + 256] * sc;

    if (sel) {
        out[b * GN + tid]       = s_vnext[tid];
        out[b * GN + tid + 256] = s_vnext[tid + 256];
    }
}

extern "C" void kernel_launch(void* const* d_in, const int* in_sizes, int n_in,
                              void* d_out, int out_size, void* d_ws, size_t ws_size,
                              hipStream_t stream) {
    const float* WL     = (const float*)d_in[0];
    const float* WR     = (const float*)d_in[1];
    const float* v_tm1  = (const float*)d_in[2];
    const float* v_t    = (const float*)d_in[3];
    const int*   ac_idx = (const int*)d_in[4];
    const int*   pc_msk = (const int*)d_in[5];
    float* out = (float*)d_out;

    const double RHO = 0.999;
    const float g     = (float)(0.5 * (log(1.0 + RHO) - log(1.0 - RHO)) / RHO);
    const float inv_n = (float)(1.0 / ((double)GN * RHO * RHO));

    dim3 grid(GB, GP);
    ghu_fused<<<grid, 256, 0, stream>>>(WL, WR, v_tm1, v_t, ac_idx, pc_msk,
                                        out, g, inv_n);
}

// Round 2
// 512.814 us; speedup vs baseline: 1.0090x; 1.0090x over previous
//
#include <hip/hip_runtime.h>
#include <math.h>

// Problem constants (fixed by the reference):
#define GP 8
#define GB 256
#define GN 512
#define GK 64

__device__ __forceinline__ void fma4(float4& acc, const float4 a, const float4 b) {
    acc.x += a.x * b.x; acc.y += a.y * b.y; acc.z += a.z * b.z; acc.w += a.w * b.w;
}
__device__ __forceinline__ float hsum4(const float4 a) {
    return (a.x + a.y) + (a.z + a.w);
}

// One block per (p, b). 4 lanes own each output row -> only 2 shfl_xor steps
// per reduction; all global loads independent + coalesced (64B per 4 lanes).
__global__ __launch_bounds__(256, 4) void ghu_fused(
    const float* __restrict__ WL,
    const float* __restrict__ WR,
    const float* __restrict__ v_tm1,
    const float* __restrict__ v_t,
    const int*   __restrict__ ac_idx,
    const int*   __restrict__ pc_mask,
    float* __restrict__ out,       // [GB*GN v_next][GP*GB*GN dWL][GP*GB*GN dWR]
    float g, float inv_n)
{
    const int b    = blockIdx.x;
    const int p    = blockIdx.y;
    const int tid  = threadIdx.x;
    const int wave = tid >> 6;
    const int lane = tid & 63;
    const int sub  = lane & 3;    // 4 lanes per row
    const int rsub = lane >> 2;   // row-within-wave, 0..15

    __shared__ float s_vtm1[GN];
    __shared__ float s_vt[GN];
    __shared__ float s_WRx[GK];
    __shared__ float s_Wx[GK];
    __shared__ float s_dWL[GN];
    __shared__ float s_vnext[GN];

    // Stage v vectors (coalesced; tiny, L2/L3-resident)
    s_vtm1[tid]       = v_tm1[b * GN + tid];
    s_vtm1[tid + 256] = v_tm1[b * GN + tid + 256];
    s_vt[tid]         = v_t[b * GN + tid];
    s_vt[tid + 256]   = v_t[b * GN + tid + 256];
    __syncthreads();

    const bool  sel   = (ac_idx[b] == p);          // block-uniform
    const float maskv = (float)pc_mask[b * GP + p];

    const float4* sv_u  = (const float4*)s_vtm1;
    const float4* sv_t4 = (const float4*)s_vt;

    // ---- Phase 1: WRx[k] = WR[p,b,k,:]·v_tm1, Wx[k] = WR[p,b,k,:]·v_t ----
    // Row k = wave*16 + rsub; lane covers float4 columns sub + 4j, j=0..31.
    {
        const float4* WR4  = (const float4*)(WR + (size_t)(p * GB + b) * (GK * GN));
        const int     k    = wave * 16 + rsub;
        const float4* rowp = WR4 + k * 128 + sub;

        float4 accA[2], accB[2];
        accA[0] = accA[1] = make_float4(0.f, 0.f, 0.f, 0.f);
        accB[0] = accB[1] = make_float4(0.f, 0.f, 0.f, 0.f);
        #pragma unroll
        for (int j = 0; j < 32; ++j) {
            const float4 a = rowp[4 * j];          // independent global loads
            const float4 u = sv_u[sub + 4 * j];
            const float4 t = sv_t4[sub + 4 * j];
            fma4(accA[j & 1], a, u);
            fma4(accB[j & 1], a, t);
        }
        float wrx = hsum4(accA[0]) + hsum4(accA[1]);
        float wx  = hsum4(accB[0]) + hsum4(accB[1]);
        wrx += __shfl_xor(wrx, 1);
        wrx += __shfl_xor(wrx, 2);
        wx  += __shfl_xor(wx, 1);
        wx  += __shfl_xor(wx, 2);
        if (sub == 0) {
            s_WRx[k] = wrx;
            s_Wx[k]  = wx;
        }
    }
    __syncthreads();

    // ---- Phase 2: WLWRx[n] = WL[p,b,n,:]·WRx (+ v_next when selected) ----
    // Row n = i*64 + wave*16 + rsub; lane covers float4 k-chunks sub + 4j, j=0..3.
    {
        // Hoist the per-lane WRx/Wx fragments once (conflict-free broadcast)
        float4 wr4[4], wx4[4];
        #pragma unroll
        for (int j = 0; j < 4; ++j) {
            wr4[j] = ((const float4*)s_WRx)[sub + 4 * j];
            wx4[j] = ((const float4*)s_Wx)[sub + 4 * j];
        }

        const float4* WL4 = (const float4*)(WL + (size_t)(p * GB + b) * (GN * GK));
        #pragma unroll
        for (int i = 0; i < 8; ++i) {
            const int     n  = i * 64 + wave * 16 + rsub;
            const float4* rp = WL4 + n * 16 + sub;
            const float4 a0 = rp[0];
            const float4 a1 = rp[4];
            const float4 a2 = rp[8];
            const float4 a3 = rp[12];

            float4 dacc = make_float4(0.f, 0.f, 0.f, 0.f);
            fma4(dacc, a0, wr4[0]); fma4(dacc, a1, wr4[1]);
            fma4(dacc, a2, wr4[2]); fma4(dacc, a3, wr4[3]);
            float d = hsum4(dacc);
            d += __shfl_xor(d, 1);
            d += __shfl_xor(d, 2);

            if (sel) {
                float4 dacc2 = make_float4(0.f, 0.f, 0.f, 0.f);
                fma4(dacc2, a0, wx4[0]); fma4(dacc2, a1, wx4[1]);
                fma4(dacc2, a2, wx4[2]); fma4(dacc2, a3, wx4[3]);
                float d2 = hsum4(dacc2);
                d2 += __shfl_xor(d2, 1);
                d2 += __shfl_xor(d2, 2);
                if (sub == 0) s_vnext[n] = tanhf(d2);
            }
            if (sub == 0) s_dWL[n] = (g * s_vt[n] - d) * maskv;
        }
    }
    __syncthreads();

    // ---- Epilogue: coalesced contiguous writes ----
    const size_t pbN = (size_t)(p * GB + b) * GN;
    float* dWL_out = out + (size_t)GB * GN + pbN;
    float* dWR_out = out + (size_t)GB * GN + (size_t)GP * GB * GN + pbN;

    dWL_out[tid]       = s_dWL[tid];
    dWL_out[tid + 256] = s_dWL[tid + 256];

    const float sc = maskv * inv_n;
    dWR_out[tid]       = s_vtm1[tid] * sc;
    dWR_out[tid + 256] = s_vtm1[tid + 256] * sc;

    if (sel) {
        out[b * GN + tid]       = s_vnext[tid];
        out[b * GN + tid + 256] = s_vnext[tid + 256];
    }
}

extern "C" void kernel_launch(void* const* d_in, const int* in_sizes, int n_in,
                              void* d_out, int out_size, void* d_ws, size_t ws_size,
                              hipStream_t stream) {
    const float* WL     = (const float*)d_in[0];
    const float* WR     = (const float*)d_in[1];
    const float* v_tm1  = (const float*)d_in[2];
    const float* v_t    = (const float*)d_in[3];
    const int*   ac_idx = (const int*)d_in[4];
    const int*   pc_msk = (const int*)d_in[5];
    float* out = (float*)d_out;

    const double RHO = 0.999;
    const float g     = (float)(0.5 * (log(1.0 + RHO) - log(1.0 - RHO)) / RHO);
    const float inv_n = (float)(1.0 / ((double)GN * RHO * RHO));

    dim3 grid(GB, GP);
    ghu_fused<<<grid, 256, 0, stream>>>(WL, WR, v_tm1, v_t, ac_idx, pc_msk,
                                        out, g, inv_n);
}